// Round 5
// baseline (68.295 us; speedup 1.0000x reference)
//
#include <hip/hip_runtime.h>
#include <hip/hip_bf16.h>

// AgentModel: B=8, N=256, TD=128, LH=128, H=128, A=5, L=2
constexpr int Bc = 8;
constexpr int Nc = 256;
constexpr int Hc = 128;
constexpr int Ac = 5;
constexpr int Mc = Bc * Nc;  // 2048
constexpr int R = 8;         // rows per block

// ---------------------------------------------------------------------------
// prep: transpose weights so GEMM k-loops read lanes-consecutive (coalesced).
//   encWt[k][o]      = encW[o][k]        (256x128 <- 128x256)
//   Mt[l][k][c]      = msgW[l][c&127][(c>>7)*128 + k]   (c<128: Wj, else Wi)
//   updWt[l][k][o]   = updW[l][o][k]
//   hW1t[k][o]       = hW1[o][k]
// dst-indexed: writes coalesced, reads scattered but L2-cached (tiny).
// Total dst elements: 32768 + 65536 + 32768 + 16384 = 147456 = 144*1024.
// ---------------------------------------------------------------------------
__global__ __launch_bounds__(256) void prep_kernel(
    const float* __restrict__ encW, const float* __restrict__ msgW,
    const float* __restrict__ updW, const float* __restrict__ hW1,
    float* __restrict__ encWt, float* __restrict__ Mt,
    float* __restrict__ updWt, float* __restrict__ hW1t) {
  const int base = blockIdx.x * 1024 + threadIdx.x;
#pragma unroll
  for (int i = 0; i < 4; ++i) {
    int id = base + i * 256;
    if (id < 32768) {
      int k = id >> 7, o = id & 127;
      encWt[id] = encW[o * 256 + k];
    } else if (id < 98304) {
      int e = id - 32768;  // l*32768 + k*256 + c
      int l = e >> 15, r = e & 32767;
      int k = r >> 8, c = r & 255;
      Mt[e] = msgW[l * 32768 + (c & 127) * 256 + ((c >> 7) << 7) + k];
    } else if (id < 131072) {
      int e = id - 98304;  // l*16384 + k*128 + o
      int l = e >> 14, r = e & 16383;
      int k = r >> 7, o = r & 127;
      updWt[e] = updW[l * 16384 + o * 128 + k];
    } else {
      int e = id - 131072;  // k*128 + o
      int k = e >> 7, o = e & 127;
      hW1t[e] = hW1[o * 128 + k];
    }
  }
}

// ---------------------------------------------------------------------------
// K1: encoder + pj/pi of layer 0.  256 blocks x 512 threads, R=8 rows/block.
// ---------------------------------------------------------------------------
__global__ __launch_bounds__(512) void k1_enc_pjpi(
    const float* __restrict__ theta, const float* __restrict__ cell,
    const float* __restrict__ encWt, const float* __restrict__ encb,
    const float* __restrict__ Mt0, float* __restrict__ h,
    float* __restrict__ pj, float* __restrict__ pi) {
  __shared__ float xs[R][256];
  __shared__ float hs[R][Hc];
  const int m0 = blockIdx.x * R;
  const int tid = threadIdx.x;

  {  // stage x = [theta|cell]: 512 threads x float4 = 2048 = 8*256 exactly
    int idx = tid * 4;
    int r = idx >> 8, d = idx & 255;
    const float* src = (d < 128) ? theta + (m0 + r) * 128 + d
                                 : cell + (m0 + r) * 128 + (d - 128);
    *reinterpret_cast<float4*>(&xs[r][d]) = *reinterpret_cast<const float4*>(src);
  }
  __syncthreads();

  const int o = tid & 127;
  const int rg = tid >> 7;  // 0..3, rows rg*2, rg*2+1
  {                         // encoder: coalesced encWt reads, broadcast LDS x
    const int r0 = rg * 2;
    float a0 = 0.f, a1 = 0.f;
#pragma unroll 8
    for (int k = 0; k < 256; ++k) {
      float w = encWt[k * 128 + o];
      a0 += w * xs[r0][k];
      a1 += w * xs[r0 + 1][k];
    }
    float b = encb[o];
    float v0 = fmaxf(a0 + b, 0.f), v1 = fmaxf(a1 + b, 0.f);
    hs[r0][o] = v0;
    hs[r0 + 1][o] = v1;
    h[(m0 + r0) * Hc + o] = v0;
    h[(m0 + r0 + 1) * Hc + o] = v1;
  }
  __syncthreads();

  {  // pj/pi layer 0: 256 cols x 2 rowgroups of 4 rows
    const int c = tid & 255;
    const int rg2 = tid >> 8;  // 0..1
    const int r0 = rg2 * 4;
    float a[4] = {0.f, 0.f, 0.f, 0.f};
#pragma unroll 8
    for (int k = 0; k < 128; ++k) {
      float w = Mt0[k * 256 + c];
      a[0] += w * hs[r0][k];
      a[1] += w * hs[r0 + 1][k];
      a[2] += w * hs[r0 + 2][k];
      a[3] += w * hs[r0 + 3][k];
    }
    float* dst = (c < 128) ? pj : pi;
    const int oc = c & 127;
#pragma unroll
    for (int r = 0; r < 4; ++r) dst[(m0 + r0 + r) * Hc + oc] = a[r];
  }
}

// ---------------------------------------------------------------------------
// K2/K3: agg(l) + upd(l) [+ pjpi(l+1) | + head]
// agg via abs identity: sum_j relu(v+s) = 0.5*(sum v + 256*s + sum|v+s|)
// ---------------------------------------------------------------------------
template <bool LAST>
__global__ __launch_bounds__(512) void k_layer(
    const float* __restrict__ pj, const float* __restrict__ pi,
    const float* __restrict__ mb, float* __restrict__ h,
    const float* __restrict__ updWt, const float* __restrict__ updb,
    const float* __restrict__ MtN, float* __restrict__ pj2,
    float* __restrict__ pi2, const float* __restrict__ hW1t,
    const float* __restrict__ hb1, const float* __restrict__ hW2,
    const float* __restrict__ hb2, float* __restrict__ out) {
  __shared__ float xs[R][Hc];  // h + agg
  __shared__ float hs[R][Hc];  // updated h
  __shared__ float zs[R][Hc];  // head z (LAST only)
  const int m0 = blockIdx.x * R;
  const int b = m0 >> 8;
  const int tid = threadIdx.x;
  const int o = tid & 127;
  const int rg = tid >> 7;  // 0..3, rows rg*2, rg*2+1
  const float* pjb = pj + b * Nc * Hc;

  {  // aggregation
    const int r0 = rg * 2;
    const float mbo = mb[o];
    float s0 = pi[(m0 + r0) * Hc + o] + mbo;
    float s1 = pi[(m0 + r0 + 1) * Hc + o] + mbo;
    float vsum = 0.f, ab0 = 0.f, ab1 = 0.f;
#pragma unroll 8
    for (int j = 0; j < Nc; ++j) {
      float v = pjb[j * Hc + o];  // coalesced, L1/L2-hot
      vsum += v;
      ab0 += fabsf(v + s0);
      ab1 += fabsf(v + s1);
    }
    float d0 = fmaxf(pj[(m0 + r0) * Hc + o] + s0, 0.f);
    float d1 = fmaxf(pj[(m0 + r0 + 1) * Hc + o] + s1, 0.f);
    float sr0 = 0.5f * (vsum + 256.f * s0 + ab0);
    float sr1 = 0.5f * (vsum + 256.f * s1 + ab1);
    xs[r0][o] = h[(m0 + r0) * Hc + o] + (sr0 - d0) * (1.f / 255.f);
    xs[r0 + 1][o] = h[(m0 + r0 + 1) * Hc + o] + (sr1 - d1) * (1.f / 255.f);
  }
  __syncthreads();

  {  // update GEMM
    const int r0 = rg * 2;
    float a0 = 0.f, a1 = 0.f;
#pragma unroll 8
    for (int k = 0; k < 128; ++k) {
      float w = updWt[k * 128 + o];
      a0 += w * xs[r0][k];
      a1 += w * xs[r0 + 1][k];
    }
    float bo = updb[o];
    float v0 = fmaxf(a0 + bo, 0.f), v1 = fmaxf(a1 + bo, 0.f);
    hs[r0][o] = v0;
    hs[r0 + 1][o] = v1;
    if (!LAST) {
      h[(m0 + r0) * Hc + o] = v0;
      h[(m0 + r0 + 1) * Hc + o] = v1;
    }
  }
  __syncthreads();

  if (!LAST) {  // pj/pi of next layer
    const int c = tid & 255;
    const int rg2 = tid >> 8;
    const int r0 = rg2 * 4;
    float a[4] = {0.f, 0.f, 0.f, 0.f};
#pragma unroll 8
    for (int k = 0; k < 128; ++k) {
      float w = MtN[k * 256 + c];
      a[0] += w * hs[r0][k];
      a[1] += w * hs[r0 + 1][k];
      a[2] += w * hs[r0 + 2][k];
      a[3] += w * hs[r0 + 3][k];
    }
    float* dst = (c < 128) ? pj2 : pi2;
    const int oc = c & 127;
#pragma unroll
    for (int r = 0; r < 4; ++r) dst[(m0 + r0 + r) * Hc + oc] = a[r];
  } else {  // head
    const int r0 = rg * 2;
    float a0 = 0.f, a1 = 0.f;
#pragma unroll 8
    for (int k = 0; k < 128; ++k) {
      float w = hW1t[k * 128 + o];
      a0 += w * hs[r0][k];
      a1 += w * hs[r0 + 1][k];
    }
    float bo = hb1[o];
    zs[r0][o] = fmaxf(a0 + bo, 0.f);
    zs[r0 + 1][o] = fmaxf(a1 + bo, 0.f);
    __syncthreads();

    if (tid < R * Ac) {  // 40 dots of length 128
      const int r = tid / Ac;
      const int a = tid % Ac;
      const float* wr2 = hW2 + a * Hc;
      float sacc = 0.f;
#pragma unroll 4
      for (int k = 0; k < 128; k += 4) {
        float4 w = *reinterpret_cast<const float4*>(wr2 + k);
        sacc += w.x * zs[r][k] + w.y * zs[r][k + 1] + w.z * zs[r][k + 2] +
                w.w * zs[r][k + 3];
      }
      out[(m0 + r) * Ac + a] = sacc + hb2[a];
    }
  }
}

// ---------------------------------------------------------------------------
extern "C" void kernel_launch(void* const* d_in, const int* in_sizes, int n_in,
                              void* d_out, int out_size, void* d_ws, size_t ws_size,
                              hipStream_t stream) {
  const float* theta = (const float*)d_in[0];
  const float* cell  = (const float*)d_in[1];
  const float* encW  = (const float*)d_in[2];
  const float* encb  = (const float*)d_in[3];
  const float* msgW  = (const float*)d_in[4];   // (2,128,256)
  const float* msgb  = (const float*)d_in[5];   // (2,128)
  const float* updW  = (const float*)d_in[6];   // (2,128,128)
  const float* updb  = (const float*)d_in[7];   // (2,128)
  const float* hW1   = (const float*)d_in[8];
  const float* hb1   = (const float*)d_in[9];
  const float* hW2   = (const float*)d_in[10];
  const float* hb2   = (const float*)d_in[11];
  float* out = (float*)d_out;

  float* ws = (float*)d_ws;
  const int MH = Mc * Hc;           // 262144
  float* h      = ws;
  float* pjA    = ws + MH;
  float* piA    = ws + 2 * MH;
  float* pjB    = ws + 3 * MH;
  float* piB    = ws + 4 * MH;
  float* encWt  = ws + 5 * MH;            // 32768
  float* Mt     = encWt + 32768;          // 2*32768
  float* updWt  = Mt + 65536;             // 2*16384
  float* hW1t   = updWt + 32768;          // 16384

  prep_kernel<<<144, 256, 0, stream>>>(encW, msgW, updW, hW1, encWt, Mt, updWt,
                                       hW1t);
  k1_enc_pjpi<<<Mc / R, 512, 0, stream>>>(theta, cell, encWt, encb, Mt, h, pjA,
                                          piA);
  k_layer<false><<<Mc / R, 512, 0, stream>>>(
      pjA, piA, msgb, h, updWt, updb, Mt + 32768, pjB, piB, hW1t, hb1, hW2,
      hb2, out);
  k_layer<true><<<Mc / R, 512, 0, stream>>>(
      pjB, piB, msgb + Hc, h, updWt + 16384, updb + Hc, nullptr, nullptr,
      nullptr, hW1t, hb1, hW2, hb2, out);
}